// Round 1
// baseline (63.997 us; speedup 1.0000x reference)
//
#include <hip/hip_runtime.h>
#include <math.h>

// TransferMatrixMethod: B=256 batches, L=64 layers (62 inner), W=512 wavelengths.
// M_layer = [[cos p, -i sin p / n],[-i n sin p, cos p]] -- real diagonal,
// pure-imaginary off-diagonal. Closed under product: carry as 4 reals
// M = [[A, i*Bi],[i*Ci, D]].
//   carry @ layer(a=cos, b=-sin/n, c=-n sin):
//     A' = A*a - Bi*c;  Bi' = A*b + Bi*a;  Ci' = Ci*a + D*c;  D' = D*a - Ci*b
// Final: E = A+1e-9 + i*Bi*n_sub ; H = D*n_sub + i*Ci
//   r = (n_in*E - H)/(n_in*E + H);  R = |num|^2/|den|^2   (division cleared)

#define TMM_B 256
#define TMM_L 64
#define TMM_W 512

__global__ __launch_bounds__(256) void tmm_kernel(
    const float* __restrict__ n_layers,   // [B][L]
    const float* __restrict__ d_layers,   // [B][L]
    const float* __restrict__ wavelengths,// [W]
    float* __restrict__ out)              // [B][W]
{
    __shared__ float s_n[TMM_L];
    __shared__ float s_nd[TMM_L];

    const int b     = blockIdx.x >> 1;           // 2 blocks per batch row
    const int wbase = (blockIdx.x & 1) << 8;     // 0 or 256
    const int tid   = threadIdx.x;

    if (tid < TMM_L) {
        float n = n_layers[b * TMM_L + tid];
        float d = d_layers[b * TMM_L + tid];
        s_n[tid]  = n;
        s_nd[tid] = n * d;
    }
    __syncthreads();

    const int w    = wbase + tid;
    const float lam = wavelengths[w];
    const float k0  = 6.283185307179586f / lam;

    float A = 1.0f, Bi = 0.0f, Ci = 0.0f, D = 1.0f;

    #pragma unroll 4
    for (int l = 1; l <= TMM_L - 2; ++l) {
        const float n   = s_n[l];               // LDS broadcast (same addr all lanes)
        const float phi = s_nd[l] * k0;
        float sp, cp;
        __sincosf(phi, &sp, &cp);
        const float bco = -sp / (n + 1e-8f);
        const float cco = -n * sp;
        const float A2 = A  * cp + (-Bi) * cco;
        const float B2 = A  * bco + Bi   * cp;
        const float C2 = Ci * cp + D     * cco;
        const float D2 = D  * cp + (-Ci) * bco;
        A = A2; Bi = B2; Ci = C2; D = D2;
    }

    const float n_in  = s_n[0];
    const float n_sub = s_n[TMM_L - 1];

    const float E_re = A + 1e-9f;       // E_in + 1e-9 (real part)
    const float E_im = Bi * n_sub;
    const float H_re = D * n_sub;
    const float H_im = Ci;

    const float num_re = n_in * E_re - H_re;
    const float num_im = n_in * E_im - H_im;
    const float den_re = n_in * E_re + H_re;
    const float den_im = n_in * E_im + H_im;

    const float R = (num_re * num_re + num_im * num_im) /
                    (den_re * den_re + den_im * den_im);

    out[b * TMM_W + w] = R;
}

extern "C" void kernel_launch(void* const* d_in, const int* in_sizes, int n_in,
                              void* d_out, int out_size, void* d_ws, size_t ws_size,
                              hipStream_t stream) {
    const float* n_layers    = (const float*)d_in[0];   // 256*64
    const float* d_layers    = (const float*)d_in[1];   // 256*64
    const float* wavelengths = (const float*)d_in[2];   // 512
    float* out = (float*)d_out;                         // 256*512

    dim3 grid(TMM_B * 2);   // 512 blocks: (batch, half-of-W)
    dim3 block(256);
    tmm_kernel<<<grid, block, 0, stream>>>(n_layers, d_layers, wavelengths, out);
}

// Round 2
// 60.173 us; speedup vs baseline: 1.0635x; 1.0635x over previous
//
#include <hip/hip_runtime.h>
#include <math.h>

// TransferMatrixMethod: B=256 batches, L=64 layers (62 inner), W=512 wavelengths.
// M_layer = [[cos p, -i sin p / n],[-i n sin p, cos p]] -- real diagonal,
// pure-imaginary off-diagonal. Closed under product: carry as 4 reals
// M = [[A, i*Bi],[i*Ci, D]].
//   carry @ layer(a=cos, b=-sin/n, c=-n sin):
//     A' = A*a - Bi*c;  Bi' = A*b + Bi*a;  Ci' = Ci*a + D*c;  D' = D*a - Ci*b
// Final: E = A+1e-9 + i*Bi*n_sub ; H = D*n_sub + i*Ci
//   r = (n_in*E - H)/(n_in*E + H);  R = |num|^2/|den|^2   (division cleared)
//
// R2 changes vs R1 (R1 = 64 us, latency-bound at 2 waves/SIMD):
//  - inner-loop divide removed: 1/(n+1e-8) precomputed into LDS at staging
//  - __sincosf replaced by native v_sin/v_cos in REVOLUTION domain:
//    phi_rev = n*d/lam  (<2 rev, in HW valid range; no range reduction, no 2*pi)
//  - full unroll so sincos/coefs pipeline ahead of the 4-FMA carry chain

#define TMM_B 256
#define TMM_L 64
#define TMM_W 512

__global__ __launch_bounds__(256) void tmm_kernel(
    const float* __restrict__ n_layers,   // [B][L]
    const float* __restrict__ d_layers,   // [B][L]
    const float* __restrict__ wavelengths,// [W]
    float* __restrict__ out)              // [B][W]
{
    __shared__ float s_n[TMM_L];
    __shared__ float s_nd[TMM_L];
    __shared__ float s_invn[TMM_L];

    const int b     = blockIdx.x >> 1;           // 2 blocks per batch row
    const int wbase = (blockIdx.x & 1) << 8;     // 0 or 256
    const int tid   = threadIdx.x;

    if (tid < TMM_L) {
        float n = n_layers[b * TMM_L + tid];
        float d = d_layers[b * TMM_L + tid];
        s_n[tid]    = n;
        s_nd[tid]   = n * d;
        s_invn[tid] = __frcp_rn(n + 1e-8f);      // hoisted out of the 62-layer loop
    }
    __syncthreads();

    const int w       = wbase + tid;
    const float lam   = wavelengths[w];
    const float ilam  = __frcp_rn(lam);          // phi in revolutions = n*d/lam

    float A = 1.0f, Bi = 0.0f, Ci = 0.0f, D = 1.0f;

    #pragma unroll
    for (int l = 1; l <= TMM_L - 2; ++l) {
        const float n    = s_n[l];               // LDS broadcast (same addr all lanes)
        const float rev  = s_nd[l] * ilam;       // < 2 revolutions
        const float sp   = __builtin_amdgcn_sinf(rev);  // v_sin_f32: sin(2*pi*rev)
        const float cp   = __builtin_amdgcn_cosf(rev);  // v_cos_f32
        const float bco  = -sp * s_invn[l];
        const float cco  = -n * sp;
        const float A2 = A  * cp - Bi * cco;
        const float B2 = A  * bco + Bi * cp;
        const float C2 = Ci * cp + D  * cco;
        const float D2 = D  * cp - Ci * bco;
        A = A2; Bi = B2; Ci = C2; D = D2;
    }

    const float n_in  = s_n[0];
    const float n_sub = s_n[TMM_L - 1];

    const float E_re = A + 1e-9f;       // E_in + 1e-9 (real part)
    const float E_im = Bi * n_sub;
    const float H_re = D * n_sub;
    const float H_im = Ci;

    const float num_re = n_in * E_re - H_re;
    const float num_im = n_in * E_im - H_im;
    const float den_re = n_in * E_re + H_re;
    const float den_im = n_in * E_im + H_im;

    const float R = (num_re * num_re + num_im * num_im) /
                    (den_re * den_re + den_im * den_im);

    out[b * TMM_W + w] = R;
}

extern "C" void kernel_launch(void* const* d_in, const int* in_sizes, int n_in,
                              void* d_out, int out_size, void* d_ws, size_t ws_size,
                              hipStream_t stream) {
    const float* n_layers    = (const float*)d_in[0];   // 256*64
    const float* d_layers    = (const float*)d_in[1];   // 256*64
    const float* wavelengths = (const float*)d_in[2];   // 512
    float* out = (float*)d_out;                         // 256*512

    dim3 grid(TMM_B * 2);   // 512 blocks: (batch, half-of-W)
    dim3 block(256);
    tmm_kernel<<<grid, block, 0, stream>>>(n_layers, d_layers, wavelengths, out);
}